// Round 16
// baseline (369.905 us; speedup 1.0000x reference)
//
#include <hip/hip_runtime.h>
#include <hip/hip_bf16.h>

// Problem constants
constexpr int B      = 4;
constexpr int LQ     = 640;
constexpr int LIM    = 1296;
constexpr int LK     = LQ + LIM;   // 1936
constexpr int DM     = 768;
constexpr int NHEAD  = 12;
constexpr int DK     = 64;
constexpr int DFF    = 3072;
constexpr int MAXD   = 100;
constexpr int M_DOC  = B * LQ;     // 2560
constexpr int M_FULL = B * LK;     // 7744
constexpr size_t ML_CNT = (size_t)B * NHEAD * LQ;   // 30720 (m,l) rows per split
constexpr int NPREP  = M_FULL * (DM / 8) / 256;     // 2904 exact
constexpr int NSPLIT = 3;          // K-split (wave parallelism)

typedef __attribute__((ext_vector_type(8))) short bf16x8_t;   // 8 bf16 = 4 VGPRs
typedef __attribute__((ext_vector_type(4))) float f32x4_t;    // MFMA C/D

__device__ __forceinline__ float b2f(__hip_bfloat16 x) { return __bfloat162float(x); }

__device__ __forceinline__ float ldf(const void* p, size_t i, int f32flag) {
    return f32flag ? ((const float*)p)[i]
                   : b2f(((const __hip_bfloat16*)p)[i]);
}

// async global->LDS, 16 bytes per lane. LDS dest = wave-uniform base + lane*16.
__device__ __forceinline__ void gl_lds16(const void* g, void* l) {
    __builtin_amdgcn_global_load_lds(
        (const __attribute__((address_space(1))) unsigned int*)g,
        (__attribute__((address_space(3))) unsigned int*)l, 16, 0, 0);
}

// ---------------------------------------------------------------------------
// Transpose 32x32 tile helper (K x N flagged -> N x K bf16).
// ---------------------------------------------------------------------------
__device__ __forceinline__ void wtrans_tile(const void* W, __hip_bfloat16* Wt,
                                            int f32, int K, int N, int n0, int k0,
                                            __hip_bfloat16 (*t)[33])
{
    const int tx = threadIdx.x & 31, ty = threadIdx.x >> 5;
#pragma unroll
    for (int j = 0; j < 4; ++j) {
        int k = ty + j * 8;
        t[k][tx] = __float2bfloat16(ldf(W, (size_t)(k0 + k) * N + n0 + tx, f32));
    }
    __syncthreads();
#pragma unroll
    for (int j = 0; j < 4; ++j) {
        int n = ty + j * 8;
        Wt[(size_t)(n0 + n) * K + k0 + tx] = t[tx][n];
    }
}

// ---------------------------------------------------------------------------
// FUSED: prep (dtype flag + concat conv -> bf16 fullA + packed coord array)
// and Wq/Wk/Wv transposes in ONE dispatch.
// Coords packed (x | y<<16), both < 1000 so 16 bits each.
// ---------------------------------------------------------------------------
__global__ __launch_bounds__(256)
void prep_wt3_kernel(const void* __restrict__ g1, int* __restrict__ flagp,
                     const void* __restrict__ im, const void* __restrict__ docqa,
                     const int* __restrict__ dqx, const int* __restrict__ dqy,
                     const int* __restrict__ imx, const int* __restrict__ imy,
                     const void* __restrict__ Wq, const void* __restrict__ Wk,
                     const void* __restrict__ Wv,
                     __hip_bfloat16* __restrict__ fullA,
                     int* __restrict__ cxy,
                     __hip_bfloat16* __restrict__ Wt3)
{
    __shared__ __hip_bfloat16 t[32][33];
    const bool f32 = ((*(const unsigned*)g1) & 0xFFFFu) == 0u;
    const int bx = blockIdx.x;

    if (bx >= NPREP) {                       // ---- wtrans3 part ----
        const int id  = bx - NPREP;          // 0..1727
        const int wid = id / 576;
        const int tt  = id % 576;
        const void* W = (wid == 0) ? Wq : (wid == 1) ? Wk : Wv;
        wtrans_tile(W, Wt3 + (size_t)wid * DM * DM, f32 ? 1 : 0, DM, DM,
                    (tt % 24) * 32, (tt / 24) * 32, t);
        return;
    }

    // ---- prep part ----
    if (bx == 0 && threadIdx.x == 0) *flagp = f32 ? 1 : 0;

    const int gid = bx * 256 + threadIdx.x;
    if (gid < B * LK) {
        int b = gid / LK, l = gid - b * LK;
        const int x = (l < LIM) ? imx[b * LIM + l] : dqx[b * LQ + l - LIM];
        const int y = (l < LIM) ? imy[b * LIM + l] : dqy[b * LQ + l - LIM];
        cxy[gid] = (x & 0xFFFF) | (y << 16);
    }

    const int row = gid / (DM / 8);
    const int col = (gid - row * (DM / 8)) * 8;
    const int b   = row / LK;
    const int l   = row - b * LK;
    const size_t srow = (l < LIM) ? ((size_t)(b * LIM + l)) * DM
                                  : ((size_t)(b * LQ + (l - LIM))) * DM;
    const void* src = (l < LIM) ? im : docqa;
    union { bf16x8_t v; __hip_bfloat16 h[8]; } pk;
    if (f32) {
        const float4* fp = (const float4*)((const float*)src + srow + col);
        float4 a = fp[0], c = fp[1];
        pk.h[0] = __float2bfloat16(a.x); pk.h[1] = __float2bfloat16(a.y);
        pk.h[2] = __float2bfloat16(a.z); pk.h[3] = __float2bfloat16(a.w);
        pk.h[4] = __float2bfloat16(c.x); pk.h[5] = __float2bfloat16(c.y);
        pk.h[6] = __float2bfloat16(c.z); pk.h[7] = __float2bfloat16(c.w);
    } else {
        pk.v = *(const bf16x8_t*)((const __hip_bfloat16*)src + srow + col);
    }
    *(bf16x8_t*)(fullA + (size_t)row * DM + col) = pk.v;
}

// ---------------------------------------------------------------------------
// Fused QKV GEMM, pure m97 structure (R10-measured best).
//   id <  732 : K/V blocks, 12 cols x 61 rows over full A (seg 1/2)
//   id >= 732 : Q   blocks,  6 cols x 20 rows over doc rows (seg 0).
// q (doc rows, *1/8) -> qout (d_out scratch); k row-major; V transposed
// per (b,h): vtb[((b*NHEAD+h)*DK + d) * LK + kk].
// ---------------------------------------------------------------------------
__global__ __launch_bounds__(256)
void qkv_gemm(const __hip_bfloat16* __restrict__ fullA,
              const __hip_bfloat16* __restrict__ Wt3,
              const void* __restrict__ bq,
              const void* __restrict__ bk,
              const void* __restrict__ bv,
              __hip_bfloat16* __restrict__ qout,
              __hip_bfloat16* __restrict__ kb,
              __hip_bfloat16* __restrict__ vtb,
              const int* __restrict__ flagp)
{
    __shared__ __hip_bfloat16 Als[128 * 32];
    __shared__ __hip_bfloat16 Bls[128 * 32];

    const int f32  = *flagp;
    const int tid  = threadIdx.x;
    const int lane = tid & 63;
    const int wave = tid >> 6;
    const int quad = lane >> 4;
    const int c16  = lane & 15;

    const int id = blockIdx.x;
    int n0, m0;
    if (id < 732) {                    // K/V over full A
        n0 = DM + (id % 12) * 128;
        m0 = (id / 12) * 128;
    } else {                           // Q over doc rows only
        const int t = id - 732;
        n0 = (t % 6) * 128;
        m0 = (t / 6) * 128;
    }
    const int seg = n0 / DM;           // 0=q 1=k 2=v

    const int wm   = (wave >> 1) * 64;
    const int wn   = (wave & 1) * 64;
    constexpr int K = DM;

    f32x4_t acc[4][4] = {};

    for (int k0 = 0; k0 < K; k0 += 32) {
#pragma unroll
        for (int p = 0; p < 2; ++p) {
            const int lin = p * 64 + lane;
            int row = wave * 32 + (lin >> 2);
            int gr  = m0 + row;
            if (seg == 0) {
                const int bb = gr / LQ;               // doc row -> full row
                gr = bb * LK + LIM + (gr - bb * LQ);
            } else if (gr > M_FULL - 1) gr = M_FULL - 1;
            gl_lds16(fullA + (size_t)gr * K + k0 + (lin & 3) * 8,
                     Als + wave * 1024 + p * 512);
        }
#pragma unroll
        for (int p = 0; p < 2; ++p) {
            const int lin = p * 64 + lane;
            const int row = wave * 32 + (lin >> 2);
            gl_lds16(Wt3 + (size_t)(n0 + row) * K + k0 + (lin & 3) * 8,
                     Bls + wave * 1024 + p * 512);
        }
        __syncthreads();

        bf16x8_t af[4], bfr[4];
#pragma unroll
        for (int i = 0; i < 4; ++i)
            af[i] = *(const bf16x8_t*)(Als + (wm + i * 16 + c16) * 32 + quad * 8);
#pragma unroll
        for (int j = 0; j < 4; ++j)
            bfr[j] = *(const bf16x8_t*)(Bls + (wn + j * 16 + c16) * 32 + quad * 8);
#pragma unroll
        for (int i = 0; i < 4; ++i)
#pragma unroll
            for (int j = 0; j < 4; ++j)
                acc[i][j] = __builtin_amdgcn_mfma_f32_16x16x32_bf16(af[i], bfr[j], acc[i][j], 0, 0, 0);
        __syncthreads();
    }

    const void* bptr = (seg == 0) ? bq : (seg == 1) ? bk : bv;
#pragma unroll
    for (int j = 0; j < 4; ++j) {
        const int col  = n0 + wn + j * 16 + c16;
        const int ncol = col - seg * DM;
        const float bj = ldf(bptr, ncol, f32);
        if (seg == 2) {
            // V transposed: vtb[((bb*NHEAD+h)*DK+d)*LK + kk]
            const int h = ncol >> 6, d = ncol & 63;
#pragma unroll
            for (int i = 0; i < 4; ++i) {
                const int rowb = m0 + wm + i * 16 + quad * 4;
                const int bb0  = rowb / LK;
                const int l0   = rowb - bb0 * LK;
                if (l0 + 3 < LK && rowb + 3 < M_FULL) {
                    union { ushort4 u4; __hip_bfloat16 hh[4]; } pk;
#pragma unroll
                    for (int r = 0; r < 4; ++r)
                        pk.hh[r] = __float2bfloat16(acc[i][j][r] + bj);
                    *(ushort4*)(vtb + ((size_t)((bb0 * NHEAD + h) * DK + d)) * LK + l0) = pk.u4;
                } else {
#pragma unroll
                    for (int r = 0; r < 4; ++r) {
                        const int row = rowb + r;
                        if (row < M_FULL) {
                            int bb = row / LK, l = row - bb * LK;
                            vtb[((size_t)((bb * NHEAD + h) * DK + d)) * LK + l] =
                                __float2bfloat16(acc[i][j][r] + bj);
                        }
                    }
                }
            }
        } else if (seg == 1) {
#pragma unroll
            for (int i = 0; i < 4; ++i) {
                const int rowb = m0 + wm + i * 16 + quad * 4;
#pragma unroll
                for (int r = 0; r < 4; ++r) {
                    const int row = rowb + r;
                    if (row < M_FULL)
                        kb[(size_t)row * DM + ncol] = __float2bfloat16(acc[i][j][r] + bj);
                }
            }
        } else {
            // Q: rows are doc rows directly (exact 2560, no guard needed)
#pragma unroll
            for (int i = 0; i < 4; ++i) {
                const int rowb = m0 + wm + i * 16 + quad * 4;
#pragma unroll
                for (int r = 0; r < 4; ++r)
                    qout[(size_t)(rowb + r) * DM + ncol] =
                        __float2bfloat16((acc[i][j][r] + bj) * 0.125f);
            }
        }
    }
}

// Standard MFMA GEMM (bias + relu) for FFN1 (R10 single-buffer, measured best).
__global__ __launch_bounds__(256)
void mfma_gemm_relu(const __hip_bfloat16* __restrict__ Abf,
                    const __hip_bfloat16* __restrict__ Wt,
                    const void* __restrict__ bias,
                    __hip_bfloat16* __restrict__ Cc,
                    const int* __restrict__ flagp,
                    int M, int N, int K)
{
    __shared__ __hip_bfloat16 Als[128 * 32];
    __shared__ __hip_bfloat16 Bls[128 * 32];

    const int f32  = *flagp;
    const int tid  = threadIdx.x;
    const int lane = tid & 63;
    const int wave = tid >> 6;
    const int quad = lane >> 4;
    const int c16  = lane & 15;
    const int n0   = blockIdx.x * 128;
    const int m0   = blockIdx.y * 128;
    const int wm   = (wave >> 1) * 64;
    const int wn   = (wave & 1) * 64;

    f32x4_t acc[4][4] = {};

    for (int k0 = 0; k0 < K; k0 += 32) {
#pragma unroll
        for (int p = 0; p < 2; ++p) {
            const int lin = p * 64 + lane;
            int row = wave * 32 + (lin >> 2);
            int gr  = m0 + row; if (gr > M - 1) gr = M - 1;
            gl_lds16(Abf + (size_t)gr * K + k0 + (lin & 3) * 8, Als + wave * 1024 + p * 512);
        }
#pragma unroll
        for (int p = 0; p < 2; ++p) {
            const int lin = p * 64 + lane;
            const int row = wave * 32 + (lin >> 2);
            gl_lds16(Wt + (size_t)(n0 + row) * K + k0 + (lin & 3) * 8,
                     Bls + wave * 1024 + p * 512);
        }
        __syncthreads();

        bf16x8_t af[4], bfr[4];
#pragma unroll
        for (int i = 0; i < 4; ++i)
            af[i] = *(const bf16x8_t*)(Als + (wm + i * 16 + c16) * 32 + quad * 8);
#pragma unroll
        for (int j = 0; j < 4; ++j)
            bfr[j] = *(const bf16x8_t*)(Bls + (wn + j * 16 + c16) * 32 + quad * 8);
#pragma unroll
        for (int i = 0; i < 4; ++i)
#pragma unroll
            for (int j = 0; j < 4; ++j)
                acc[i][j] = __builtin_amdgcn_mfma_f32_16x16x32_bf16(af[i], bfr[j], acc[i][j], 0, 0, 0);
        __syncthreads();
    }

#pragma unroll
    for (int j = 0; j < 4; ++j) {
        const int col = n0 + wn + j * 16 + c16;
        const float bj = ldf(bias, col, f32);
#pragma unroll
        for (int i = 0; i < 4; ++i) {
            const int rowb = m0 + wm + i * 16 + quad * 4;
#pragma unroll
            for (int r = 0; r < 4; ++r) {
                const int row = rowb + r;
                if (row < M) {
                    float v = fmaxf(acc[i][j][r] + bj, 0.f);
                    Cc[(size_t)row * N + col] = __float2bfloat16(v);
                }
            }
        }
    }
}

// Split-K MFMA GEMM: f32 atomic accumulate (dest pre-zeroed), grid z = chunk.
// (Fallback path for skF when d_out cannot host an f32 partial.)
__global__ __launch_bounds__(256)
void sk_gemm(const __hip_bfloat16* __restrict__ Abf,
             const __hip_bfloat16* __restrict__ Wt,
             float* __restrict__ Cc,
             int M, int N, int K, int S)
{
    __shared__ __hip_bfloat16 Als[128 * 32];
    __shared__ __hip_bfloat16 Bls[128 * 32];

    const int tid  = threadIdx.x;
    const int lane = tid & 63;
    const int wave = tid >> 6;
    const int quad = lane >> 4;
    const int c16  = lane & 15;
    const int n0   = blockIdx.x * 128;
    const int m0   = blockIdx.y * 128;
    const int wm   = (wave >> 1) * 64;
    const int wn   = (wave & 1) * 64;
    const int kchunk = K / S;
    const int kbeg = blockIdx.z * kchunk;

    f32x4_t acc[4][4] = {};

    for (int k0 = kbeg; k0 < kbeg + kchunk; k0 += 32) {
#pragma unroll
        for (int p = 0; p < 2; ++p) {
            const int lin = p * 64 + lane;
            int row = wave * 32 + (lin >> 2);
            int gr  = m0 + row; if (gr > M - 1) gr = M - 1;
            gl_lds16(Abf + (size_t)gr * K + k0 + (lin & 3) * 8, Als + wave * 1024 + p * 512);
        }
#pragma unroll
        for (int p = 0; p < 2; ++p) {
            const int lin = p * 64 + lane;
            const int row = wave * 32 + (lin >> 2);
            gl_lds16(Wt + (size_t)(n0 + row) * K + k0 + (lin & 3) * 8,
                     Bls + wave * 1024 + p * 512);
        }
        __syncthreads();

        bf16x8_t af[4], bfr[4];
#pragma unroll
        for (int i = 0; i < 4; ++i)
            af[i] = *(const bf16x8_t*)(Als + (wm + i * 16 + c16) * 32 + quad * 8);
#pragma unroll
        for (int j = 0; j < 4; ++j)
            bfr[j] = *(const bf16x8_t*)(Bls + (wn + j * 16 + c16) * 32 + quad * 8);
#pragma unroll
        for (int i = 0; i < 4; ++i)
#pragma unroll
            for (int j = 0; j < 4; ++j)
                acc[i][j] = __builtin_amdgcn_mfma_f32_16x16x32_bf16(af[i], bfr[j], acc[i][j], 0, 0, 0);
        __syncthreads();
    }

#pragma unroll
    for (int j = 0; j < 4; ++j) {
        const int col = n0 + wn + j * 16 + c16;
#pragma unroll
        for (int i = 0; i < 4; ++i) {
            const int rowb = m0 + wm + i * 16 + quad * 4;
#pragma unroll
            for (int r = 0; r < 4; ++r) {
                const int row = rowb + r;
                if (row < M) atomicAdd(&Cc[(size_t)row * N + col], acc[i][j][r]);
            }
        }
    }
}

// ---------------------------------------------------------------------------
// Split-K S=2 GEMM with DIRECT STORES into two partial buffers — zero atomics
// (R15-measured: skWo atomic->direct = −13 us; R16 applies the same proven
// transform to skF). z=0 -> C0 (K [0,K/2)), z=1 -> C1 (K [K/2,K)).
// Consumer sums C0+C1.
// ---------------------------------------------------------------------------
__global__ __launch_bounds__(256)
void sk2_gemm(const __hip_bfloat16* __restrict__ Abf,
              const __hip_bfloat16* __restrict__ Wt,
              float* __restrict__ C0,
              float* __restrict__ C1,
              int M, int N, int K)
{
    __shared__ __hip_bfloat16 Als[128 * 32];
    __shared__ __hip_bfloat16 Bls[128 * 32];

    const int tid  = threadIdx.x;
    const int lane = tid & 63;
    const int wave = tid >> 6;
    const int quad = lane >> 4;
    const int c16  = lane & 15;
    const int n0   = blockIdx.x * 128;
    const int m0   = blockIdx.y * 128;
    const int wm   = (wave >> 1) * 64;
    const int wn   = (wave & 1) * 64;
    const int kchunk = K / 2;
    const int kbeg = blockIdx.z * kchunk;
    float* __restrict__ Cc = blockIdx.z ? C1 : C0;

    f32x4_t acc[4][4] = {};

    for (int k0 = kbeg; k0 < kbeg + kchunk; k0 += 32) {
#pragma unroll
        for (int p = 0; p < 2; ++p) {
            const int lin = p * 64 + lane;
            int row = wave * 32 + (lin >> 2);
            int gr  = m0 + row; if (gr > M - 1) gr = M - 1;
            gl_lds16(Abf + (size_t)gr * K + k0 + (lin & 3) * 8, Als + wave * 1024 + p * 512);
        }
#pragma unroll
        for (int p = 0; p < 2; ++p) {
            const int lin = p * 64 + lane;
            const int row = wave * 32 + (lin >> 2);
            gl_lds16(Wt + (size_t)(n0 + row) * K + k0 + (lin & 3) * 8,
                     Bls + wave * 1024 + p * 512);
        }
        __syncthreads();

        bf16x8_t af[4], bfr[4];
#pragma unroll
        for (int i = 0; i < 4; ++i)
            af[i] = *(const bf16x8_t*)(Als + (wm + i * 16 + c16) * 32 + quad * 8);
#pragma unroll
        for (int j = 0; j < 4; ++j)
            bfr[j] = *(const bf16x8_t*)(Bls + (wn + j * 16 + c16) * 32 + quad * 8);
#pragma unroll
        for (int i = 0; i < 4; ++i)
#pragma unroll
            for (int j = 0; j < 4; ++j)
                acc[i][j] = __builtin_amdgcn_mfma_f32_16x16x32_bf16(af[i], bfr[j], acc[i][j], 0, 0, 0);
        __syncthreads();
    }

#pragma unroll
    for (int j = 0; j < 4; ++j) {
        const int col = n0 + wn + j * 16 + c16;
#pragma unroll
        for (int i = 0; i < 4; ++i) {
            const int rowb = m0 + wm + i * 16 + quad * 4;
#pragma unroll
            for (int r = 0; r < 4; ++r) {
                const int row = rowb + r;
                if (row < M) Cc[(size_t)row * N + col] = acc[i][j][r];
            }
        }
    }
}

// ---------------------------------------------------------------------------
// MFMA flash attention (R10-measured best, ~78 us; bracketed as a local
// optimum by five structural experiments). K-split S=3; double-buffered K/V
// staging with prefetch-before-compute + ONE barrier/tile; LDS bf16 bias
// tables; register online softmax with deferred l-reduce; packed coords.
// ---------------------------------------------------------------------------
__global__ __launch_bounds__(256)
void attn_part_kernel(const __hip_bfloat16* __restrict__ Qb,
                      const __hip_bfloat16* __restrict__ Kb,
                      const __hip_bfloat16* __restrict__ Vtb,
                      const int* __restrict__ cxy,
                      const void* __restrict__ bias_x,
                      const void* __restrict__ bias_y,
                      __hip_bfloat16* __restrict__ pparts,
                      float* __restrict__ mlbase,
                      const int* __restrict__ flagp)
{
    constexpr int QT = 64, KT = 64;
    constexpr int QROW = 72;                   // 144 B stride: 16-B aligned + bank-rotating
    __shared__ char PQraw[QT * QROW * 2];      // 9216 B: Qs (8192) UNION Ps
    __shared__ __hip_bfloat16 Ks[2 * KT * DK]; // 16 KB double-buffered
    __shared__ __hip_bfloat16 Vs[2 * DK * KT]; // 16 KB double-buffered ([d][kk])
    __shared__ __hip_bfloat16 bxs[2 * MAXD + 1], bys[2 * MAXD + 1];  // bf16: 804 B
    __hip_bfloat16* Qs = (__hip_bfloat16*)PQraw;
    __hip_bfloat16* Ps = (__hip_bfloat16*)PQraw;

    const int f32  = *flagp;
    const int tid  = threadIdx.x;
    const int lane = tid & 63;
    const int wave = tid >> 6;
    const int quad = lane >> 4;
    const int c16  = lane & 15;

    // XCD-swizzled decode: id%48 = (b,h); rest selects (split, q-tile)
    const int id   = blockIdx.x;
    const int bh   = id % 48;
    const int rest = id / 48;          // 0..29
    const int s    = rest % NSPLIT;
    const int q0   = (rest / NSPLIT) * QT;
    const int b    = bh / NHEAD;
    const int h    = bh - b * NHEAD;
    const int kbeg = s * 640;
    const int kend = (s == NSPLIT - 1) ? LK : kbeg + 640;

    __hip_bfloat16* Op = pparts + (size_t)s * M_DOC * DM;
    float* mp = mlbase + (size_t)s * 2 * ML_CNT;
    float* lp = mp + ML_CNT;

    for (int i = tid; i < 2 * MAXD + 1; i += 256) {
        bxs[i] = __float2bfloat16(ldf(bias_x, (size_t)i * NHEAD + h, f32));
        bys[i] = __float2bfloat16(ldf(bias_y, (size_t)i * NHEAD + h, f32));
    }

    const __hip_bfloat16* kbase = Kb + ((size_t)(b * LK)) * DM + h * DK;
    const __hip_bfloat16* vbase = Vtb + ((size_t)((b * NHEAD + h) * DK)) * LK;
    const __hip_bfloat16* qbase = Qb + ((size_t)(b * LQ + q0)) * DM + h * DK;
    const int* cb_ = cxy + b * LK;

    const int rsub = lane >> 3;                 // 0..7
    const int cgl  = (lane & 7) ^ (rsub & 7);   // XOR chunk swizzle (global side)

    // ---- stage Q once (swizzled chunks; wave stages its own 16 rows) ----
#pragma unroll
    for (int p = 0; p < 2; ++p) {
        const int rl = wave * 16 + p * 8 + rsub;
        gl_lds16(qbase + (size_t)rl * DM + cgl * 8, Qs + (wave * 16 + p * 8) * DK);
    }

    // ---- stage K/V tile 0 into buffer 0 (prologue) ----
#pragma unroll
    for (int p = 0; p < 2; ++p) {
        const int rl = wave * 16 + p * 8 + rsub;
        int gr = kbeg + rl; if (gr > LK - 1) gr = LK - 1;
        gl_lds16(kbase + (size_t)gr * DM + cgl * 8, Ks + (wave * 16 + p * 8) * DK);
    }
#pragma unroll
    for (int p = 0; p < 2; ++p) {
        const int dl = wave * 16 + p * 8 + rsub;
        int kks = kbeg + cgl * 8; if (kks > LK - 8) kks = LK - 8;
        gl_lds16(vbase + (size_t)dl * LK + kks, Vs + (wave * 16 + p * 8) * KT);
    }

    int qxp[4], qyp[4];
#pragma unroll
    for (int r = 0; r < 4; ++r) {
        const int v = cb_[LIM + q0 + wave * 16 + quad * 4 + r];
        qxp[r] = (v & 0xFFFF) + MAXD;
        qyp[r] = (v >> 16) + MAXD;
    }

    __syncthreads();   // drains Q + tile0 staging + bias writes

    // loop-invariant Q fragments from swizzled LDS
    const int sw  = c16 & 7;
    const int cA0 = (quad ^ sw) * 8;
    const int cA1 = ((quad + 4) ^ sw) * 8;
    const int rQ  = wave * 16 + c16;
    const bf16x8_t aq0 = *(const bf16x8_t*)(Qs + rQ * DK + cA0);
    const bf16x8_t aq1 = *(const bf16x8_t*)(Qs + rQ * DK + cA1);
    // secure Q fragments in VGPRs before LDS space is reused as Ps
    asm volatile("s_waitcnt lgkmcnt(0)" ::: "memory");
    __syncthreads();

    f32x4_t O[4] = {};
    float m_r[4], l_r[4];
#pragma unroll
    for (int r = 0; r < 4; ++r) { m_r[r] = -1e30f; l_r[r] = 0.f; }

    const int nt = (kend - kbeg + KT - 1) / KT;
    int bi = 0;
    for (int t = 0; t < nt; ++t) {
        const int k0 = kbeg + t * KT;
        // ---- prefetch NEXT tile into the other buffer (clamped; branch-free)
        {
            const int kn = k0 + KT;
            __hip_bfloat16* Kd = Ks + (bi ^ 1) * (KT * DK);
            __hip_bfloat16* Vd = Vs + (bi ^ 1) * (KT * DK);
#pragma unroll
            for (int p = 0; p < 2; ++p) {
                const int rl = wave * 16 + p * 8 + rsub;
                int gr = kn + rl; if (gr > LK - 1) gr = LK - 1;
                gl_lds16(kbase + (size_t)gr * DM + cgl * 8, Kd + (wave * 16 + p * 8) * DK);
            }
#pragma unroll
            for (int p = 0; p < 2; ++p) {
                const int dl = wave * 16 + p * 8 + rsub;
                int kks = kn + cgl * 8; if (kks > LK - 8) kks = LK - 8;
                gl_lds16(vbase + (size_t)dl * LK + kks, Vd + (wave * 16 + p * 8) * KT);
            }
        }
        const __hip_bfloat16* Kc = Ks + bi * (KT * DK);
        const __hip_bfloat16* Vc = Vs + bi * (KT * DK);

        // ---- scores from LDS K fragments ----
        f32x4_t S[4];
#pragma unroll
        for (int jn = 0; jn < 4; ++jn) {
            const int rK = jn * 16 + c16;
            bf16x8_t bk0 = *(const bf16x8_t*)(Kc + rK * DK + cA0);
            bf16x8_t bk1 = *(const bf16x8_t*)(Kc + rK * DK + cA1);
            f32x4_t acc = {0.f, 0.f, 0.f, 0.f};
            acc = __builtin_amdgcn_mfma_f32_16x16x32_bf16(aq0, bk0, acc, 0, 0, 0);
            acc = __builtin_amdgcn_mfma_f32_16x16x32_bf16(aq1, bk1, acc, 0, 0, 0);
            S[jn] = acc;
        }
        // ---- bias + tail mask (packed coord gather, med3 clamp) ----
#pragma unroll
        for (int jn = 0; jn < 4; ++jn) {
            const int kg = k0 + jn * 16 + c16;
            const bool ok = kg < LK;
            const int kv = cb_[ok ? kg : LK - 1];
            const int kx = kv & 0xFFFF, ky = kv >> 16;
#pragma unroll
            for (int r = 0; r < 4; ++r) {
                int rx = min(max(qxp[r] - kx, 0), 2 * MAXD);   // v_med3
                int ry = min(max(qyp[r] - ky, 0), 2 * MAXD);
                float v = S[jn][r] + b2f(bxs[rx]) + b2f(bys[ry]);
                S[jn][r] = ok ? v : -1e30f;
            }
        }
        // ---- online softmax: row max reduced, l kept as PER-LANE partial ----
        float alpha[4];
#pragma unroll
        for (int r = 0; r < 4; ++r) {
            float mx = fmaxf(fmaxf(S[0][r], S[1][r]), fmaxf(S[2][r], S[3][r]));
            mx = fmaxf(mx, __shfl_xor(mx, 1));
            mx = fmaxf(mx, __shfl_xor(mx, 2));
            mx = fmaxf(mx, __shfl_xor(mx, 4));
            mx = fmaxf(mx, __shfl_xor(mx, 8));
            const float mt = fmaxf(m_r[r], mx);
            const float al = __expf(m_r[r] - mt);
            float sum = 0.f;
#pragma unroll
            for (int jn = 0; jn < 4; ++jn) {
                float p = __expf(S[jn][r] - mt);
                S[jn][r] = p;
                sum += p;
            }
            m_r[r] = mt;
            l_r[r] = l_r[r] * al + sum;   // per-lane partial; reduced once at end
            alpha[r] = al;
        }
        // ---- P -> LDS (wave-private rows; no barrier) + O rescale ----
#pragma unroll
        for (int jn = 0; jn < 4; ++jn)
#pragma unroll
            for (int r = 0; r < 4; ++r)
                Ps[(wave * 16 + quad * 4 + r) * QROW + jn * 16 + c16] = __float2bfloat16(S[jn][r]);
#pragma unroll
        for (int jd = 0; jd < 4; ++jd)
#pragma unroll
            for (int r = 0; r < 4; ++r) O[jd][r] *= alpha[r];
        // ---- PV: A from Ps, B from swizzled Vs ----
        bf16x8_t ap0 = *(const bf16x8_t*)(Ps + (wave * 16 + c16) * QROW + quad * 8);
        bf16x8_t ap1 = *(const bf16x8_t*)(Ps + (wave * 16 + c16) * QROW + 32 + quad * 8);
#pragma unroll
        for (int jd = 0; jd < 4; ++jd) {
            const int rV = jd * 16 + c16;
            bf16x8_t bv0 = *(const bf16x8_t*)(Vc + rV * KT + cA0);
            bf16x8_t bv1 = *(const bf16x8_t*)(Vc + rV * KT + cA1);
            O[jd] = __builtin_amdgcn_mfma_f32_16x16x32_bf16(ap0, bv0, O[jd], 0, 0, 0);
            O[jd] = __builtin_amdgcn_mfma_f32_16x16x32_bf16(ap1, bv1, O[jd], 0, 0, 0);
        }
        // ONE barrier per tile: implicit vmcnt(0) drains the prefetch (hidden
        // under this tile's compute) + joins waves before buffer swap.
        __syncthreads();
        bi ^= 1;
    }

    // Epilogue: unnormalized partial O + (m,l); l reduced across the
    // 16-lane row group HERE (once) instead of every k-tile.
#pragma unroll
    for (int r = 0; r < 4; ++r) {
        float ls = l_r[r];
        ls += __shfl_xor(ls, 1);
        ls += __shfl_xor(ls, 2);
        ls += __shfl_xor(ls, 4);
        ls += __shfl_xor(ls, 8);
        const int ql = wave * 16 + quad * 4 + r;
        const size_t grow = (size_t)(b * LQ + q0 + ql);
#pragma unroll
        for (int jd = 0; jd < 4; ++jd)
            Op[grow * DM + h * DK + jd * 16 + c16] = __float2bfloat16(O[jd][r]);
        if (c16 == 0) {
            size_t mli = ((size_t)b * NHEAD + h) * LQ + q0 + ql;
            mp[mli] = m_r[r];
            lp[mli] = ls;
        }
    }
}

// ---------------------------------------------------------------------------
// FUSED: 3-way merge of the K-splits -> ctx + Wo transpose (R1 [0,1.18M)) +
// W1/W2 transposes (R3) in ONE dispatch.
// ---------------------------------------------------------------------------
__global__ __launch_bounds__(256)
void merge_wt_kernel(const __hip_bfloat16* __restrict__ pparts,
                     const float* __restrict__ mlbase,
                     __hip_bfloat16* __restrict__ ctx,
                     const void* __restrict__ Wo,
                     __hip_bfloat16* __restrict__ WtO,
                     const void* __restrict__ W1,
                     const void* __restrict__ W2,
                     __hip_bfloat16* __restrict__ W1t,
                     __hip_bfloat16* __restrict__ W2t,
                     const int* __restrict__ flagp)
{
    __shared__ __hip_bfloat16 t[32][33];
    const int bx = blockIdx.x;

    if (bx >= M_DOC + 576) {                // ---- wtransW part ----
        const int id = bx - (M_DOC + 576);  // 0..4607
        const int f32 = *flagp;
        const bool second = id >= 2304;
        const void* W = second ? W2 : W1;
        __hip_bfloat16* dst = second ? W2t : W1t;
        const int K = second ? DFF : DM;
        const int N = second ? DM : DFF;
        const int tt = second ? id - 2304 : id;
        const int nt = N / 32;
        wtrans_tile(W, dst, f32, K, N, (tt % nt) * 32, (tt / nt) * 32, t);
        return;
    }
    if (bx >= M_DOC) {                      // ---- wtransO part ----
        const int tt = bx - M_DOC;
        wtrans_tile(Wo, WtO, *flagp, DM, DM, (tt % 24) * 32, (tt / 24) * 32, t);
        return;
    }

    // ---- merge part (3-way) ----
    const int row = bx;                     // (b,q) flat
    const int b = row / LQ, q = row - b * LQ;
    const int tid = threadIdx.x;
#pragma unroll
    for (int i = 0; i < 3; ++i) {
        const int c = tid + i * 256;
        const int h = c >> 6;
        const size_t mli = ((size_t)b * NHEAD + h) * LQ + q;
        const float m0 = mlbase[mli],                  l0 = mlbase[ML_CNT + mli];
        const float m1 = mlbase[2 * ML_CNT + mli],     l1 = mlbase[3 * ML_CNT + mli];
        const float m2 = mlbase[4 * ML_CNT + mli],     l2 = mlbase[5 * ML_CNT + mli];
        const float mm = fmaxf(m0, fmaxf(m1, m2));
        const float w0 = __expf(m0 - mm), w1 = __expf(m1 - mm), w2 = __expf(m2 - mm);
        const float denom = l0 * w0 + l1 * w1 + l2 * w2;
        const size_t idx = (size_t)row * DM + c;
        const float v = (b2f(pparts[idx]) * w0 +
                         b2f(pparts[(size_t)M_DOC * DM + idx]) * w1 +
                         b2f(pparts[(size_t)2 * M_DOC * DM + idx]) * w2) / denom;
        ctx[idx] = __float2bfloat16(v);
    }
}

// ---------------------------------------------------------------------------
// LayerNorm over 768 with folded bias: x = A + acc1 + (acc2) + bias2.
//  MODE 0: A = flagged Xin -> bf16 ws out.
//  MODE 1: A = bf16 Xb     -> flagged-dtype d_out.
// Both modes sum Xf2f plus (optionally, non-null) Xf2g partials.
// zbuf (optional): zeroed after reads (atomic-fallback accumulator prep;
// may alias Xf2g — per-thread read-before-write at identical idx, safe).
// Wave shfl reduce + 1 barrier.
// ---------------------------------------------------------------------------
template<int MODE>
__global__ __launch_bounds__(256)
void ln_kernel(const void* __restrict__ Xin,
               const __hip_bfloat16* __restrict__ Xb,
               const float* __restrict__ Xf2f,
               const float* __restrict__ Xf2g,
               const void* __restrict__ bias2,
               const void* __restrict__ g,
               const void* __restrict__ be,
               __hip_bfloat16* __restrict__ outb,
               void* __restrict__ outv,
               float* __restrict__ zbuf,
               const int* __restrict__ flagp)
{
    __shared__ float red1[4], red2[4];
    const int f32 = *flagp;
    const int row = blockIdx.x;
    const int tid = threadIdx.x;
    const int lane = tid & 63;
    const int wave = tid >> 6;

    float x[3];
#pragma unroll
    for (int i = 0; i < 3; ++i) {
        int c = tid + i * 256;
        size_t idx = (size_t)row * DM + c;
        float a  = (MODE == 0) ? ldf(Xin, idx, f32) : b2f(Xb[idx]);
        float acc = Xf2f[idx];
        if (Xf2g) acc += Xf2g[idx];
        x[i] = a + acc + ldf(bias2, c, f32);
    }
    float s1 = x[0] + x[1] + x[2];
    float s2 = x[0] * x[0] + x[1] * x[1] + x[2] * x[2];
#pragma unroll
    for (int off = 32; off > 0; off >>= 1) {
        s1 += __shfl_xor(s1, off);
        s2 += __shfl_xor(s2, off);
    }
    if (lane == 0) { red1[wave] = s1; red2[wave] = s2; }
    __syncthreads();
    s1 = red1[0] + red1[1] + red1[2] + red1[3];
    s2 = red2[0] + red2[1] + red2[2] + red2[3];
    float mu   = s1 * (1.f / DM);
    float var  = s2 * (1.f / DM) - mu * mu;
    float rstd = rsqrtf(var + 1e-5f);
#pragma unroll
    for (int i = 0; i < 3; ++i) {
        int c = tid + i * 256;
        size_t idx = (size_t)row * DM + c;
        float v = (x[i] - mu) * rstd * ldf(g, c, f32) + ldf(be, c, f32);
        if (MODE == 0) {
            outb[idx] = __float2bfloat16(v);
        } else {
            if (f32) ((float*)outv)[idx] = v;
            else     ((__hip_bfloat16*)outv)[idx] = __float2bfloat16(v);
        }
        if (zbuf) zbuf[idx] = 0.f;
    }
}

// ---------------------------------------------------------------------------
extern "C" void kernel_launch(void* const* d_in, const int* in_sizes, int n_in,
                              void* d_out, int out_size, void* d_ws, size_t ws_size,
                              hipStream_t stream)
{
    const void* docqa = d_in[0];
    const void* im    = d_in[1];
    const int* dqx = (const int*)d_in[2];
    const int* dqy = (const int*)d_in[3];
    const int* imx = (const int*)d_in[4];
    const int* imy = (const int*)d_in[5];
    const void* Wq = d_in[6];
    const void* bq = d_in[7];
    const void* Wk = d_in[8];
    const void* bk = d_in[9];
    const void* Wv = d_in[10];
    const void* bv = d_in[11];
    const void* Wo = d_in[12];
    const void* bo = d_in[13];
    const void* bias_x = d_in[14];
    const void* bias_y = d_in[15];
    const void* W1 = d_in[16];
    const void* b1 = d_in[17];
    const void* W2 = d_in[18];
    const void* b2 = d_in[19];
    const void* g1  = d_in[20];
    const void* be1 = d_in[21];
    const void* g2  = d_in[22];
    const void* be2 = d_in[23];

    // Workspace pool: 39.6 MB, proven since round 3 (DO NOT GROW).
    //   flag @0; R1 3.93M; R2 11.89M; R3 11.89M; R4 11.89M   [bytes]
    // R1: Wt3 (dead after qkv) -> ml [1.18M,1.92M); cxy tail (dead after attn)
    //     -> WtO [0,1.18M) (dead after skWo) -> first part of mid
    // R2 (kb): k row-major (dead after attn) -> a0 f32 [0,7.86M) (skWo partial
    //     0, dead after LN1) -> rest of mid
    // R3 (vtb): V^T (dead after attn) -> W1t[0,4.72M)+W2t[4.72,9.44M)
    // R4 (cb): fullA (dead after qkv) -> p0/p1/p2 [0,11.79M) -> ctx/src1 (p0);
    //     a1 f32 [3.93,11.79M) (skWo partial 1, read by LN1) -> f0 (skF
    //     partial 0 / atomic acc, same region)
    // d_out: q bf16 scratch (dead after attn) -> f1 (skF partial 1, f32,
    //     only when out_size fits) -> final output (LN2; per-thread
    //     read-before-write at identical idx over f1)
    char* w = (char*)d_ws;
    int*            flagp = (int*)w;
    __hip_bfloat16* qR  = (__hip_bfloat16*)(w + 256);
    __hip_bfloat16* kb  = qR + (size_t)M_DOC  * DM;
    __hip_bfloat16* vtb = kb + (size_t)M_FULL * DM;
    __hip_bfloat16* cb  = vtb + (size_t)M_FULL * DM;
    char* cbB = (char*)cb;
    char* r1B = (char*)qR;

    __hip_bfloat16* fullA = cb;
    __hip_bfloat16* Wt3  = qR;
    int*            cxyp = (int*)(r1B + 3538944);     // R1 spare tail (31 KB)
    __hip_bfloat16* WtO  = qR;
    __hip_bfloat16* qout = (__hip_bfloat16*)d_out;
    __hip_bfloat16* pparts = cb;                      // 3 partials, contiguous
    float*          mlb  = (float*)(r1B + 1179648);   // over dead Wt3, after WtO
    __hip_bfloat16* ctx  = cb;
    __hip_bfloat16* src1 = cb;
    float*          a0   = (float*)kb;                // skWo partial 0 (R2)
    float*          a1   = (float*)(cbB + 3932160);   // skWo partial 1 (R4)
    float*          f0   = (float*)(cbB + 3932160);   // skF partial 0 (= a1 region, after LN1)
    __hip_bfloat16* W1t  = vtb;
    __hip_bfloat16* W2t  = vtb + (size_t)DFF * DM;
    __hip_bfloat16* mid  = qR;

    // skF direct-store partial 1 lives in d_out when the output buffer is
    // f32-sized; otherwise fall back to the atomic S=4 path.
    const bool skf_direct = (size_t)out_size >= (size_t)M_DOC * DM * sizeof(float);
    float* f1 = (float*)d_out;

    dim3 blk(256);

    // fused: flag + fullA conversion + packed coords + Wq/Wk/Wv transposes
    prep_wt3_kernel<<<dim3(NPREP + 3 * 576), blk, 0, stream>>>(
        g1, flagp, im, docqa, dqx, dqy, imx, imy, Wq, Wk, Wv, fullA, cxyp, Wt3);
    // fused q/k/v projection (R10 single-buffer structure)
    qkv_gemm<<<dim3(732 + 120), blk, 0, stream>>>(
        fullA, Wt3, bq, bk, bv, qout, kb, vtb, flagp);
    // attention, K-split S=3, double-buffered staging, 1 barrier/tile
    attn_part_kernel<<<dim3(48 * 30), blk, 0, stream>>>(
        qout, kb, vtb, cxyp, bias_x, bias_y, pparts, mlb, flagp);
    // fused: 3-way merge -> ctx + Wo transpose + W1/W2 transposes
    merge_wt_kernel<<<dim3(M_DOC + 576 + 4608), blk, 0, stream>>>(
        pparts, mlb, ctx, Wo, WtO, W1, W2, W1t, W2t, flagp);
    // attn_out: split-K S=2 DIRECT-STORE partials (R15-measured win)
    sk2_gemm<<<dim3(DM / 128, M_DOC / 128, 2), blk, 0, stream>>>(
        ctx, WtO, a0, a1, M_DOC, DM, DM);
    // src1 = LN(docqa + a0 + a1 + bo); zero f0 only if skF needs atomics
    ln_kernel<0><<<dim3(M_DOC), blk, 0, stream>>>(
        docqa, nullptr, a0, a1, bo, g1, be1, src1, nullptr,
        skf_direct ? nullptr : f0, flagp);
    // mid = relu(src1 @ W1 + b1) -> R1+R2 (WtO/cxy/ml/a0 dead)
    mfma_gemm_relu<<<dim3(DFF / 128, M_DOC / 128), blk, 0, stream>>>(
        src1, W1t, b1, mid, flagp, M_DOC, DFF, DM);
    if (skf_direct) {
        // ffn: split-K S=2 DIRECT-STORE partials f0 (R4) + f1 (d_out scratch)
        sk2_gemm<<<dim3(DM / 128, M_DOC / 128, 2), blk, 0, stream>>>(
            mid, W2t, f0, f1, M_DOC, DM, DFF);
        // out = LN(src1 + f0 + f1 + b2) -> d_out (reads f1 then overwrites)
        ln_kernel<1><<<dim3(M_DOC), blk, 0, stream>>>(
            nullptr, src1, f0, f1, b2, g2, be2, nullptr, d_out, nullptr, flagp);
    } else {
        // fallback: atomic S=4 into pre-zeroed f0
        sk_gemm<<<dim3(DM / 128, M_DOC / 128, 4), blk, 0, stream>>>(
            mid, W2t, f0, M_DOC, DM, DFF, 4);
        ln_kernel<1><<<dim3(M_DOC), blk, 0, stream>>>(
            nullptr, src1, f0, nullptr, b2, g2, be2, nullptr, d_out, nullptr, flagp);
    }
}

// Round 17
// 363.980 us; speedup vs baseline: 1.0163x; 1.0163x over previous
//
#include <hip/hip_runtime.h>
#include <hip/hip_bf16.h>

// Problem constants
constexpr int B      = 4;
constexpr int LQ     = 640;
constexpr int LIM    = 1296;
constexpr int LK     = LQ + LIM;   // 1936
constexpr int DM     = 768;
constexpr int NHEAD  = 12;
constexpr int DK     = 64;
constexpr int DFF    = 3072;
constexpr int MAXD   = 100;
constexpr int M_DOC  = B * LQ;     // 2560
constexpr int M_FULL = B * LK;     // 7744
constexpr size_t ML_CNT = (size_t)B * NHEAD * LQ;   // 30720 (m,l) rows per split
constexpr int NPREP  = M_FULL * (DM / 8) / 256;     // 2904 exact
constexpr int NSPLIT = 3;          // K-split (wave parallelism)

typedef __attribute__((ext_vector_type(8))) short bf16x8_t;   // 8 bf16 = 4 VGPRs
typedef __attribute__((ext_vector_type(4))) float f32x4_t;    // MFMA C/D

__device__ __forceinline__ float b2f(__hip_bfloat16 x) { return __bfloat162float(x); }

__device__ __forceinline__ float ldf(const void* p, size_t i, int f32flag) {
    return f32flag ? ((const float*)p)[i]
                   : b2f(((const __hip_bfloat16*)p)[i]);
}

// async global->LDS, 16 bytes per lane. LDS dest = wave-uniform base + lane*16.
__device__ __forceinline__ void gl_lds16(const void* g, void* l) {
    __builtin_amdgcn_global_load_lds(
        (const __attribute__((address_space(1))) unsigned int*)g,
        (__attribute__((address_space(3))) unsigned int*)l, 16, 0, 0);
}

// ---------------------------------------------------------------------------
// Transpose 32x32 tile helper (K x N flagged -> N x K bf16).
// ---------------------------------------------------------------------------
__device__ __forceinline__ void wtrans_tile(const void* W, __hip_bfloat16* Wt,
                                            int f32, int K, int N, int n0, int k0,
                                            __hip_bfloat16 (*t)[33])
{
    const int tx = threadIdx.x & 31, ty = threadIdx.x >> 5;
#pragma unroll
    for (int j = 0; j < 4; ++j) {
        int k = ty + j * 8;
        t[k][tx] = __float2bfloat16(ldf(W, (size_t)(k0 + k) * N + n0 + tx, f32));
    }
    __syncthreads();
#pragma unroll
    for (int j = 0; j < 4; ++j) {
        int n = ty + j * 8;
        Wt[(size_t)(n0 + n) * K + k0 + tx] = t[tx][n];
    }
}

// ---------------------------------------------------------------------------
// FUSED: prep (dtype flag + concat conv -> bf16 fullA + packed coord array)
// and Wq/Wk/Wv transposes in ONE dispatch.
// Coords packed (x | y<<16), both < 1000 so 16 bits each.
// ---------------------------------------------------------------------------
__global__ __launch_bounds__(256)
void prep_wt3_kernel(const void* __restrict__ g1, int* __restrict__ flagp,
                     const void* __restrict__ im, const void* __restrict__ docqa,
                     const int* __restrict__ dqx, const int* __restrict__ dqy,
                     const int* __restrict__ imx, const int* __restrict__ imy,
                     const void* __restrict__ Wq, const void* __restrict__ Wk,
                     const void* __restrict__ Wv,
                     __hip_bfloat16* __restrict__ fullA,
                     int* __restrict__ cxy,
                     __hip_bfloat16* __restrict__ Wt3)
{
    __shared__ __hip_bfloat16 t[32][33];
    const bool f32 = ((*(const unsigned*)g1) & 0xFFFFu) == 0u;
    const int bx = blockIdx.x;

    if (bx >= NPREP) {                       // ---- wtrans3 part ----
        const int id  = bx - NPREP;          // 0..1727
        const int wid = id / 576;
        const int tt  = id % 576;
        const void* W = (wid == 0) ? Wq : (wid == 1) ? Wk : Wv;
        wtrans_tile(W, Wt3 + (size_t)wid * DM * DM, f32 ? 1 : 0, DM, DM,
                    (tt % 24) * 32, (tt / 24) * 32, t);
        return;
    }

    // ---- prep part ----
    if (bx == 0 && threadIdx.x == 0) *flagp = f32 ? 1 : 0;

    const int gid = bx * 256 + threadIdx.x;
    if (gid < B * LK) {
        int b = gid / LK, l = gid - b * LK;
        const int x = (l < LIM) ? imx[b * LIM + l] : dqx[b * LQ + l - LIM];
        const int y = (l < LIM) ? imy[b * LIM + l] : dqy[b * LQ + l - LIM];
        cxy[gid] = (x & 0xFFFF) | (y << 16);
    }

    const int row = gid / (DM / 8);
    const int col = (gid - row * (DM / 8)) * 8;
    const int b   = row / LK;
    const int l   = row - b * LK;
    const size_t srow = (l < LIM) ? ((size_t)(b * LIM + l)) * DM
                                  : ((size_t)(b * LQ + (l - LIM))) * DM;
    const void* src = (l < LIM) ? im : docqa;
    union { bf16x8_t v; __hip_bfloat16 h[8]; } pk;
    if (f32) {
        const float4* fp = (const float4*)((const float*)src + srow + col);
        float4 a = fp[0], c = fp[1];
        pk.h[0] = __float2bfloat16(a.x); pk.h[1] = __float2bfloat16(a.y);
        pk.h[2] = __float2bfloat16(a.z); pk.h[3] = __float2bfloat16(a.w);
        pk.h[4] = __float2bfloat16(c.x); pk.h[5] = __float2bfloat16(c.y);
        pk.h[6] = __float2bfloat16(c.z); pk.h[7] = __float2bfloat16(c.w);
    } else {
        pk.v = *(const bf16x8_t*)((const __hip_bfloat16*)src + srow + col);
    }
    *(bf16x8_t*)(fullA + (size_t)row * DM + col) = pk.v;
}

// ---------------------------------------------------------------------------
// Fused QKV GEMM, pure m97 structure (R10-measured best).
//   id <  732 : K/V blocks, 12 cols x 61 rows over full A (seg 1/2)
//   id >= 732 : Q   blocks,  6 cols x 20 rows over doc rows (seg 0).
// q (doc rows, *1/8) -> qout (d_out scratch); k row-major; V transposed
// per (b,h): vtb[((b*NHEAD+h)*DK + d) * LK + kk].
// ---------------------------------------------------------------------------
__global__ __launch_bounds__(256)
void qkv_gemm(const __hip_bfloat16* __restrict__ fullA,
              const __hip_bfloat16* __restrict__ Wt3,
              const void* __restrict__ bq,
              const void* __restrict__ bk,
              const void* __restrict__ bv,
              __hip_bfloat16* __restrict__ qout,
              __hip_bfloat16* __restrict__ kb,
              __hip_bfloat16* __restrict__ vtb,
              const int* __restrict__ flagp)
{
    __shared__ __hip_bfloat16 Als[128 * 32];
    __shared__ __hip_bfloat16 Bls[128 * 32];

    const int f32  = *flagp;
    const int tid  = threadIdx.x;
    const int lane = tid & 63;
    const int wave = tid >> 6;
    const int quad = lane >> 4;
    const int c16  = lane & 15;

    const int id = blockIdx.x;
    int n0, m0;
    if (id < 732) {                    // K/V over full A
        n0 = DM + (id % 12) * 128;
        m0 = (id / 12) * 128;
    } else {                           // Q over doc rows only
        const int t = id - 732;
        n0 = (t % 6) * 128;
        m0 = (t / 6) * 128;
    }
    const int seg = n0 / DM;           // 0=q 1=k 2=v

    const int wm   = (wave >> 1) * 64;
    const int wn   = (wave & 1) * 64;
    constexpr int K = DM;

    f32x4_t acc[4][4] = {};

    for (int k0 = 0; k0 < K; k0 += 32) {
#pragma unroll
        for (int p = 0; p < 2; ++p) {
            const int lin = p * 64 + lane;
            int row = wave * 32 + (lin >> 2);
            int gr  = m0 + row;
            if (seg == 0) {
                const int bb = gr / LQ;               // doc row -> full row
                gr = bb * LK + LIM + (gr - bb * LQ);
            } else if (gr > M_FULL - 1) gr = M_FULL - 1;
            gl_lds16(fullA + (size_t)gr * K + k0 + (lin & 3) * 8,
                     Als + wave * 1024 + p * 512);
        }
#pragma unroll
        for (int p = 0; p < 2; ++p) {
            const int lin = p * 64 + lane;
            const int row = wave * 32 + (lin >> 2);
            gl_lds16(Wt3 + (size_t)(n0 + row) * K + k0 + (lin & 3) * 8,
                     Bls + wave * 1024 + p * 512);
        }
        __syncthreads();

        bf16x8_t af[4], bfr[4];
#pragma unroll
        for (int i = 0; i < 4; ++i)
            af[i] = *(const bf16x8_t*)(Als + (wm + i * 16 + c16) * 32 + quad * 8);
#pragma unroll
        for (int j = 0; j < 4; ++j)
            bfr[j] = *(const bf16x8_t*)(Bls + (wn + j * 16 + c16) * 32 + quad * 8);
#pragma unroll
        for (int i = 0; i < 4; ++i)
#pragma unroll
            for (int j = 0; j < 4; ++j)
                acc[i][j] = __builtin_amdgcn_mfma_f32_16x16x32_bf16(af[i], bfr[j], acc[i][j], 0, 0, 0);
        __syncthreads();
    }

    const void* bptr = (seg == 0) ? bq : (seg == 1) ? bk : bv;
#pragma unroll
    for (int j = 0; j < 4; ++j) {
        const int col  = n0 + wn + j * 16 + c16;
        const int ncol = col - seg * DM;
        const float bj = ldf(bptr, ncol, f32);
        if (seg == 2) {
            // V transposed: vtb[((bb*NHEAD+h)*DK+d)*LK + kk]
            const int h = ncol >> 6, d = ncol & 63;
#pragma unroll
            for (int i = 0; i < 4; ++i) {
                const int rowb = m0 + wm + i * 16 + quad * 4;
                const int bb0  = rowb / LK;
                const int l0   = rowb - bb0 * LK;
                if (l0 + 3 < LK && rowb + 3 < M_FULL) {
                    union { ushort4 u4; __hip_bfloat16 hh[4]; } pk;
#pragma unroll
                    for (int r = 0; r < 4; ++r)
                        pk.hh[r] = __float2bfloat16(acc[i][j][r] + bj);
                    *(ushort4*)(vtb + ((size_t)((bb0 * NHEAD + h) * DK + d)) * LK + l0) = pk.u4;
                } else {
#pragma unroll
                    for (int r = 0; r < 4; ++r) {
                        const int row = rowb + r;
                        if (row < M_FULL) {
                            int bb = row / LK, l = row - bb * LK;
                            vtb[((size_t)((bb * NHEAD + h) * DK + d)) * LK + l] =
                                __float2bfloat16(acc[i][j][r] + bj);
                        }
                    }
                }
            }
        } else if (seg == 1) {
#pragma unroll
            for (int i = 0; i < 4; ++i) {
                const int rowb = m0 + wm + i * 16 + quad * 4;
#pragma unroll
                for (int r = 0; r < 4; ++r) {
                    const int row = rowb + r;
                    if (row < M_FULL)
                        kb[(size_t)row * DM + ncol] = __float2bfloat16(acc[i][j][r] + bj);
                }
            }
        } else {
            // Q: rows are doc rows directly (exact 2560, no guard needed)
#pragma unroll
            for (int i = 0; i < 4; ++i) {
                const int rowb = m0 + wm + i * 16 + quad * 4;
#pragma unroll
                for (int r = 0; r < 4; ++r)
                    qout[(size_t)(rowb + r) * DM + ncol] =
                        __float2bfloat16((acc[i][j][r] + bj) * 0.125f);
            }
        }
    }
}

// Standard MFMA GEMM (bias + relu) for FFN1 (R10 single-buffer, measured best).
__global__ __launch_bounds__(256)
void mfma_gemm_relu(const __hip_bfloat16* __restrict__ Abf,
                    const __hip_bfloat16* __restrict__ Wt,
                    const void* __restrict__ bias,
                    __hip_bfloat16* __restrict__ Cc,
                    const int* __restrict__ flagp,
                    int M, int N, int K)
{
    __shared__ __hip_bfloat16 Als[128 * 32];
    __shared__ __hip_bfloat16 Bls[128 * 32];

    const int f32  = *flagp;
    const int tid  = threadIdx.x;
    const int lane = tid & 63;
    const int wave = tid >> 6;
    const int quad = lane >> 4;
    const int c16  = lane & 15;
    const int n0   = blockIdx.x * 128;
    const int m0   = blockIdx.y * 128;
    const int wm   = (wave >> 1) * 64;
    const int wn   = (wave & 1) * 64;

    f32x4_t acc[4][4] = {};

    for (int k0 = 0; k0 < K; k0 += 32) {
#pragma unroll
        for (int p = 0; p < 2; ++p) {
            const int lin = p * 64 + lane;
            int row = wave * 32 + (lin >> 2);
            int gr  = m0 + row; if (gr > M - 1) gr = M - 1;
            gl_lds16(Abf + (size_t)gr * K + k0 + (lin & 3) * 8, Als + wave * 1024 + p * 512);
        }
#pragma unroll
        for (int p = 0; p < 2; ++p) {
            const int lin = p * 64 + lane;
            const int row = wave * 32 + (lin >> 2);
            gl_lds16(Wt + (size_t)(n0 + row) * K + k0 + (lin & 3) * 8,
                     Bls + wave * 1024 + p * 512);
        }
        __syncthreads();

        bf16x8_t af[4], bfr[4];
#pragma unroll
        for (int i = 0; i < 4; ++i)
            af[i] = *(const bf16x8_t*)(Als + (wm + i * 16 + c16) * 32 + quad * 8);
#pragma unroll
        for (int j = 0; j < 4; ++j)
            bfr[j] = *(const bf16x8_t*)(Bls + (wn + j * 16 + c16) * 32 + quad * 8);
#pragma unroll
        for (int i = 0; i < 4; ++i)
#pragma unroll
            for (int j = 0; j < 4; ++j)
                acc[i][j] = __builtin_amdgcn_mfma_f32_16x16x32_bf16(af[i], bfr[j], acc[i][j], 0, 0, 0);
        __syncthreads();
    }

#pragma unroll
    for (int j = 0; j < 4; ++j) {
        const int col = n0 + wn + j * 16 + c16;
        const float bj = ldf(bias, col, f32);
#pragma unroll
        for (int i = 0; i < 4; ++i) {
            const int rowb = m0 + wm + i * 16 + quad * 4;
#pragma unroll
            for (int r = 0; r < 4; ++r) {
                const int row = rowb + r;
                if (row < M) {
                    float v = fmaxf(acc[i][j][r] + bj, 0.f);
                    Cc[(size_t)row * N + col] = __float2bfloat16(v);
                }
            }
        }
    }
}

// Split-K MFMA GEMM: f32 atomic accumulate (dest pre-zeroed), grid z = chunk.
// (Fallback path for skF when d_out cannot host an f32 partial.)
__global__ __launch_bounds__(256)
void sk_gemm(const __hip_bfloat16* __restrict__ Abf,
             const __hip_bfloat16* __restrict__ Wt,
             float* __restrict__ Cc,
             int M, int N, int K, int S)
{
    __shared__ __hip_bfloat16 Als[128 * 32];
    __shared__ __hip_bfloat16 Bls[128 * 32];

    const int tid  = threadIdx.x;
    const int lane = tid & 63;
    const int wave = tid >> 6;
    const int quad = lane >> 4;
    const int c16  = lane & 15;
    const int n0   = blockIdx.x * 128;
    const int m0   = blockIdx.y * 128;
    const int wm   = (wave >> 1) * 64;
    const int wn   = (wave & 1) * 64;
    const int kchunk = K / S;
    const int kbeg = blockIdx.z * kchunk;

    f32x4_t acc[4][4] = {};

    for (int k0 = kbeg; k0 < kbeg + kchunk; k0 += 32) {
#pragma unroll
        for (int p = 0; p < 2; ++p) {
            const int lin = p * 64 + lane;
            int row = wave * 32 + (lin >> 2);
            int gr  = m0 + row; if (gr > M - 1) gr = M - 1;
            gl_lds16(Abf + (size_t)gr * K + k0 + (lin & 3) * 8, Als + wave * 1024 + p * 512);
        }
#pragma unroll
        for (int p = 0; p < 2; ++p) {
            const int lin = p * 64 + lane;
            const int row = wave * 32 + (lin >> 2);
            gl_lds16(Wt + (size_t)(n0 + row) * K + k0 + (lin & 3) * 8,
                     Bls + wave * 1024 + p * 512);
        }
        __syncthreads();

        bf16x8_t af[4], bfr[4];
#pragma unroll
        for (int i = 0; i < 4; ++i)
            af[i] = *(const bf16x8_t*)(Als + (wm + i * 16 + c16) * 32 + quad * 8);
#pragma unroll
        for (int j = 0; j < 4; ++j)
            bfr[j] = *(const bf16x8_t*)(Bls + (wn + j * 16 + c16) * 32 + quad * 8);
#pragma unroll
        for (int i = 0; i < 4; ++i)
#pragma unroll
            for (int j = 0; j < 4; ++j)
                acc[i][j] = __builtin_amdgcn_mfma_f32_16x16x32_bf16(af[i], bfr[j], acc[i][j], 0, 0, 0);
        __syncthreads();
    }

#pragma unroll
    for (int j = 0; j < 4; ++j) {
        const int col = n0 + wn + j * 16 + c16;
#pragma unroll
        for (int i = 0; i < 4; ++i) {
            const int rowb = m0 + wm + i * 16 + quad * 4;
#pragma unroll
            for (int r = 0; r < 4; ++r) {
                const int row = rowb + r;
                if (row < M) atomicAdd(&Cc[(size_t)row * N + col], acc[i][j][r]);
            }
        }
    }
}

// ---------------------------------------------------------------------------
// Split-K S=2 GEMM with DIRECT STORES into two partial buffers — zero atomics
// (R15-measured: skWo atomic->direct = −13 us; same transform applied to skF).
// z=0 -> C0 (K [0,K/2)), z=1 -> C1 (K [K/2,K)). Consumer sums C0+C1.
// ---------------------------------------------------------------------------
__global__ __launch_bounds__(256)
void sk2_gemm(const __hip_bfloat16* __restrict__ Abf,
              const __hip_bfloat16* __restrict__ Wt,
              float* __restrict__ C0,
              float* __restrict__ C1,
              int M, int N, int K)
{
    __shared__ __hip_bfloat16 Als[128 * 32];
    __shared__ __hip_bfloat16 Bls[128 * 32];

    const int tid  = threadIdx.x;
    const int lane = tid & 63;
    const int wave = tid >> 6;
    const int quad = lane >> 4;
    const int c16  = lane & 15;
    const int n0   = blockIdx.x * 128;
    const int m0   = blockIdx.y * 128;
    const int wm   = (wave >> 1) * 64;
    const int wn   = (wave & 1) * 64;
    const int kchunk = K / 2;
    const int kbeg = blockIdx.z * kchunk;
    float* __restrict__ Cc = blockIdx.z ? C1 : C0;

    f32x4_t acc[4][4] = {};

    for (int k0 = kbeg; k0 < kbeg + kchunk; k0 += 32) {
#pragma unroll
        for (int p = 0; p < 2; ++p) {
            const int lin = p * 64 + lane;
            int row = wave * 32 + (lin >> 2);
            int gr  = m0 + row; if (gr > M - 1) gr = M - 1;
            gl_lds16(Abf + (size_t)gr * K + k0 + (lin & 3) * 8, Als + wave * 1024 + p * 512);
        }
#pragma unroll
        for (int p = 0; p < 2; ++p) {
            const int lin = p * 64 + lane;
            const int row = wave * 32 + (lin >> 2);
            gl_lds16(Wt + (size_t)(n0 + row) * K + k0 + (lin & 3) * 8,
                     Bls + wave * 1024 + p * 512);
        }
        __syncthreads();

        bf16x8_t af[4], bfr[4];
#pragma unroll
        for (int i = 0; i < 4; ++i)
            af[i] = *(const bf16x8_t*)(Als + (wm + i * 16 + c16) * 32 + quad * 8);
#pragma unroll
        for (int j = 0; j < 4; ++j)
            bfr[j] = *(const bf16x8_t*)(Bls + (wn + j * 16 + c16) * 32 + quad * 8);
#pragma unroll
        for (int i = 0; i < 4; ++i)
#pragma unroll
            for (int j = 0; j < 4; ++j)
                acc[i][j] = __builtin_amdgcn_mfma_f32_16x16x32_bf16(af[i], bfr[j], acc[i][j], 0, 0, 0);
        __syncthreads();
    }

#pragma unroll
    for (int j = 0; j < 4; ++j) {
        const int col = n0 + wn + j * 16 + c16;
#pragma unroll
        for (int i = 0; i < 4; ++i) {
            const int rowb = m0 + wm + i * 16 + quad * 4;
#pragma unroll
            for (int r = 0; r < 4; ++r) {
                const int row = rowb + r;
                if (row < M) Cc[(size_t)row * N + col] = acc[i][j][r];
            }
        }
    }
}

// ---------------------------------------------------------------------------
// MFMA flash attention (R10-measured best, ~78 us; bracketed as a local
// optimum by five structural experiments). K-split S=3; double-buffered K/V
// staging with prefetch-before-compute + ONE barrier/tile; LDS bf16 bias
// tables; register online softmax with deferred l-reduce; packed coords.
// ---------------------------------------------------------------------------
__global__ __launch_bounds__(256)
void attn_part_kernel(const __hip_bfloat16* __restrict__ Qb,
                      const __hip_bfloat16* __restrict__ Kb,
                      const __hip_bfloat16* __restrict__ Vtb,
                      const int* __restrict__ cxy,
                      const void* __restrict__ bias_x,
                      const void* __restrict__ bias_y,
                      __hip_bfloat16* __restrict__ pparts,
                      float* __restrict__ mlbase,
                      const int* __restrict__ flagp)
{
    constexpr int QT = 64, KT = 64;
    constexpr int QROW = 72;                   // 144 B stride: 16-B aligned + bank-rotating
    __shared__ char PQraw[QT * QROW * 2];      // 9216 B: Qs (8192) UNION Ps
    __shared__ __hip_bfloat16 Ks[2 * KT * DK]; // 16 KB double-buffered
    __shared__ __hip_bfloat16 Vs[2 * DK * KT]; // 16 KB double-buffered ([d][kk])
    __shared__ __hip_bfloat16 bxs[2 * MAXD + 1], bys[2 * MAXD + 1];  // bf16: 804 B
    __hip_bfloat16* Qs = (__hip_bfloat16*)PQraw;
    __hip_bfloat16* Ps = (__hip_bfloat16*)PQraw;

    const int f32  = *flagp;
    const int tid  = threadIdx.x;
    const int lane = tid & 63;
    const int wave = tid >> 6;
    const int quad = lane >> 4;
    const int c16  = lane & 15;

    // XCD-swizzled decode: id%48 = (b,h); rest selects (split, q-tile)
    const int id   = blockIdx.x;
    const int bh   = id % 48;
    const int rest = id / 48;          // 0..29
    const int s    = rest % NSPLIT;
    const int q0   = (rest / NSPLIT) * QT;
    const int b    = bh / NHEAD;
    const int h    = bh - b * NHEAD;
    const int kbeg = s * 640;
    const int kend = (s == NSPLIT - 1) ? LK : kbeg + 640;

    __hip_bfloat16* Op = pparts + (size_t)s * M_DOC * DM;
    float* mp = mlbase + (size_t)s * 2 * ML_CNT;
    float* lp = mp + ML_CNT;

    for (int i = tid; i < 2 * MAXD + 1; i += 256) {
        bxs[i] = __float2bfloat16(ldf(bias_x, (size_t)i * NHEAD + h, f32));
        bys[i] = __float2bfloat16(ldf(bias_y, (size_t)i * NHEAD + h, f32));
    }

    const __hip_bfloat16* kbase = Kb + ((size_t)(b * LK)) * DM + h * DK;
    const __hip_bfloat16* vbase = Vtb + ((size_t)((b * NHEAD + h) * DK)) * LK;
    const __hip_bfloat16* qbase = Qb + ((size_t)(b * LQ + q0)) * DM + h * DK;
    const int* cb_ = cxy + b * LK;

    const int rsub = lane >> 3;                 // 0..7
    const int cgl  = (lane & 7) ^ (rsub & 7);   // XOR chunk swizzle (global side)

    // ---- stage Q once (swizzled chunks; wave stages its own 16 rows) ----
#pragma unroll
    for (int p = 0; p < 2; ++p) {
        const int rl = wave * 16 + p * 8 + rsub;
        gl_lds16(qbase + (size_t)rl * DM + cgl * 8, Qs + (wave * 16 + p * 8) * DK);
    }

    // ---- stage K/V tile 0 into buffer 0 (prologue) ----
#pragma unroll
    for (int p = 0; p < 2; ++p) {
        const int rl = wave * 16 + p * 8 + rsub;
        int gr = kbeg + rl; if (gr > LK - 1) gr = LK - 1;
        gl_lds16(kbase + (size_t)gr * DM + cgl * 8, Ks + (wave * 16 + p * 8) * DK);
    }
#pragma unroll
    for (int p = 0; p < 2; ++p) {
        const int dl = wave * 16 + p * 8 + rsub;
        int kks = kbeg + cgl * 8; if (kks > LK - 8) kks = LK - 8;
        gl_lds16(vbase + (size_t)dl * LK + kks, Vs + (wave * 16 + p * 8) * KT);
    }

    int qxp[4], qyp[4];
#pragma unroll
    for (int r = 0; r < 4; ++r) {
        const int v = cb_[LIM + q0 + wave * 16 + quad * 4 + r];
        qxp[r] = (v & 0xFFFF) + MAXD;
        qyp[r] = (v >> 16) + MAXD;
    }

    __syncthreads();   // drains Q + tile0 staging + bias writes

    // loop-invariant Q fragments from swizzled LDS
    const int sw  = c16 & 7;
    const int cA0 = (quad ^ sw) * 8;
    const int cA1 = ((quad + 4) ^ sw) * 8;
    const int rQ  = wave * 16 + c16;
    const bf16x8_t aq0 = *(const bf16x8_t*)(Qs + rQ * DK + cA0);
    const bf16x8_t aq1 = *(const bf16x8_t*)(Qs + rQ * DK + cA1);
    // secure Q fragments in VGPRs before LDS space is reused as Ps
    asm volatile("s_waitcnt lgkmcnt(0)" ::: "memory");
    __syncthreads();

    f32x4_t O[4] = {};
    float m_r[4], l_r[4];
#pragma unroll
    for (int r = 0; r < 4; ++r) { m_r[r] = -1e30f; l_r[r] = 0.f; }

    const int nt = (kend - kbeg + KT - 1) / KT;
    int bi = 0;
    for (int t = 0; t < nt; ++t) {
        const int k0 = kbeg + t * KT;
        // ---- prefetch NEXT tile into the other buffer (clamped; branch-free)
        {
            const int kn = k0 + KT;
            __hip_bfloat16* Kd = Ks + (bi ^ 1) * (KT * DK);
            __hip_bfloat16* Vd = Vs + (bi ^ 1) * (KT * DK);
#pragma unroll
            for (int p = 0; p < 2; ++p) {
                const int rl = wave * 16 + p * 8 + rsub;
                int gr = kn + rl; if (gr > LK - 1) gr = LK - 1;
                gl_lds16(kbase + (size_t)gr * DM + cgl * 8, Kd + (wave * 16 + p * 8) * DK);
            }
#pragma unroll
            for (int p = 0; p < 2; ++p) {
                const int dl = wave * 16 + p * 8 + rsub;
                int kks = kn + cgl * 8; if (kks > LK - 8) kks = LK - 8;
                gl_lds16(vbase + (size_t)dl * LK + kks, Vd + (wave * 16 + p * 8) * KT);
            }
        }
        const __hip_bfloat16* Kc = Ks + bi * (KT * DK);
        const __hip_bfloat16* Vc = Vs + bi * (KT * DK);

        // ---- scores from LDS K fragments ----
        f32x4_t S[4];
#pragma unroll
        for (int jn = 0; jn < 4; ++jn) {
            const int rK = jn * 16 + c16;
            bf16x8_t bk0 = *(const bf16x8_t*)(Kc + rK * DK + cA0);
            bf16x8_t bk1 = *(const bf16x8_t*)(Kc + rK * DK + cA1);
            f32x4_t acc = {0.f, 0.f, 0.f, 0.f};
            acc = __builtin_amdgcn_mfma_f32_16x16x32_bf16(aq0, bk0, acc, 0, 0, 0);
            acc = __builtin_amdgcn_mfma_f32_16x16x32_bf16(aq1, bk1, acc, 0, 0, 0);
            S[jn] = acc;
        }
        // ---- bias + tail mask (packed coord gather, med3 clamp) ----
#pragma unroll
        for (int jn = 0; jn < 4; ++jn) {
            const int kg = k0 + jn * 16 + c16;
            const bool ok = kg < LK;
            const int kv = cb_[ok ? kg : LK - 1];
            const int kx = kv & 0xFFFF, ky = kv >> 16;
#pragma unroll
            for (int r = 0; r < 4; ++r) {
                int rx = min(max(qxp[r] - kx, 0), 2 * MAXD);   // v_med3
                int ry = min(max(qyp[r] - ky, 0), 2 * MAXD);
                float v = S[jn][r] + b2f(bxs[rx]) + b2f(bys[ry]);
                S[jn][r] = ok ? v : -1e30f;
            }
        }
        // ---- online softmax: row max reduced, l kept as PER-LANE partial ----
        float alpha[4];
#pragma unroll
        for (int r = 0; r < 4; ++r) {
            float mx = fmaxf(fmaxf(S[0][r], S[1][r]), fmaxf(S[2][r], S[3][r]));
            mx = fmaxf(mx, __shfl_xor(mx, 1));
            mx = fmaxf(mx, __shfl_xor(mx, 2));
            mx = fmaxf(mx, __shfl_xor(mx, 4));
            mx = fmaxf(mx, __shfl_xor(mx, 8));
            const float mt = fmaxf(m_r[r], mx);
            const float al = __expf(m_r[r] - mt);
            float sum = 0.f;
#pragma unroll
            for (int jn = 0; jn < 4; ++jn) {
                float p = __expf(S[jn][r] - mt);
                S[jn][r] = p;
                sum += p;
            }
            m_r[r] = mt;
            l_r[r] = l_r[r] * al + sum;   // per-lane partial; reduced once at end
            alpha[r] = al;
        }
        // ---- P -> LDS (wave-private rows; no barrier) + O rescale ----
#pragma unroll
        for (int jn = 0; jn < 4; ++jn)
#pragma unroll
            for (int r = 0; r < 4; ++r)
                Ps[(wave * 16 + quad * 4 + r) * QROW + jn * 16 + c16] = __float2bfloat16(S[jn][r]);
#pragma unroll
        for (int jd = 0; jd < 4; ++jd)
#pragma unroll
            for (int r = 0; r < 4; ++r) O[jd][r] *= alpha[r];
        // ---- PV: A from Ps, B from swizzled Vs ----
        bf16x8_t ap0 = *(const bf16x8_t*)(Ps + (wave * 16 + c16) * QROW + quad * 8);
        bf16x8_t ap1 = *(const bf16x8_t*)(Ps + (wave * 16 + c16) * QROW + 32 + quad * 8);
#pragma unroll
        for (int jd = 0; jd < 4; ++jd) {
            const int rV = jd * 16 + c16;
            bf16x8_t bv0 = *(const bf16x8_t*)(Vc + rV * KT + cA0);
            bf16x8_t bv1 = *(const bf16x8_t*)(Vc + rV * KT + cA1);
            O[jd] = __builtin_amdgcn_mfma_f32_16x16x32_bf16(ap0, bv0, O[jd], 0, 0, 0);
            O[jd] = __builtin_amdgcn_mfma_f32_16x16x32_bf16(ap1, bv1, O[jd], 0, 0, 0);
        }
        // ONE barrier per tile: implicit vmcnt(0) drains the prefetch (hidden
        // under this tile's compute) + joins waves before buffer swap.
        __syncthreads();
        bi ^= 1;
    }

    // Epilogue: unnormalized partial O + (m,l); l reduced across the
    // 16-lane row group HERE (once) instead of every k-tile.
#pragma unroll
    for (int r = 0; r < 4; ++r) {
        float ls = l_r[r];
        ls += __shfl_xor(ls, 1);
        ls += __shfl_xor(ls, 2);
        ls += __shfl_xor(ls, 4);
        ls += __shfl_xor(ls, 8);
        const int ql = wave * 16 + quad * 4 + r;
        const size_t grow = (size_t)(b * LQ + q0 + ql);
#pragma unroll
        for (int jd = 0; jd < 4; ++jd)
            Op[grow * DM + h * DK + jd * 16 + c16] = __float2bfloat16(O[jd][r]);
        if (c16 == 0) {
            size_t mli = ((size_t)b * NHEAD + h) * LQ + q0 + ql;
            mp[mli] = m_r[r];
            lp[mli] = ls;
        }
    }
}

// ---------------------------------------------------------------------------
// FUSED: 3-way merge of the K-splits -> ctx + Wo transpose (R1 [0,1.18M)) +
// W1/W2 transposes (R3) in ONE dispatch.
// ---------------------------------------------------------------------------
__global__ __launch_bounds__(256)
void merge_wt_kernel(const __hip_bfloat16* __restrict__ pparts,
                     const float* __restrict__ mlbase,
                     __hip_bfloat16* __restrict__ ctx,
                     const void* __restrict__ Wo,
                     __hip_bfloat16* __restrict__ WtO,
                     const void* __restrict__ W1,
                     const void* __restrict__ W2,
                     __hip_bfloat16* __restrict__ W1t,
                     __hip_bfloat16* __restrict__ W2t,
                     const int* __restrict__ flagp)
{
    __shared__ __hip_bfloat16 t[32][33];
    const int bx = blockIdx.x;

    if (bx >= M_DOC + 576) {                // ---- wtransW part ----
        const int id = bx - (M_DOC + 576);  // 0..4607
        const int f32 = *flagp;
        const bool second = id >= 2304;
        const void* W = second ? W2 : W1;
        __hip_bfloat16* dst = second ? W2t : W1t;
        const int K = second ? DFF : DM;
        const int N = second ? DM : DFF;
        const int tt = second ? id - 2304 : id;
        const int nt = N / 32;
        wtrans_tile(W, dst, f32, K, N, (tt % nt) * 32, (tt / nt) * 32, t);
        return;
    }
    if (bx >= M_DOC) {                      // ---- wtransO part ----
        const int tt = bx - M_DOC;
        wtrans_tile(Wo, WtO, *flagp, DM, DM, (tt % 24) * 32, (tt / 24) * 32, t);
        return;
    }

    // ---- merge part (3-way) ----
    const int row = bx;                     // (b,q) flat
    const int b = row / LQ, q = row - b * LQ;
    const int tid = threadIdx.x;
#pragma unroll
    for (int i = 0; i < 3; ++i) {
        const int c = tid + i * 256;
        const int h = c >> 6;
        const size_t mli = ((size_t)b * NHEAD + h) * LQ + q;
        const float m0 = mlbase[mli],                  l0 = mlbase[ML_CNT + mli];
        const float m1 = mlbase[2 * ML_CNT + mli],     l1 = mlbase[3 * ML_CNT + mli];
        const float m2 = mlbase[4 * ML_CNT + mli],     l2 = mlbase[5 * ML_CNT + mli];
        const float mm = fmaxf(m0, fmaxf(m1, m2));
        const float w0 = __expf(m0 - mm), w1 = __expf(m1 - mm), w2 = __expf(m2 - mm);
        const float denom = l0 * w0 + l1 * w1 + l2 * w2;
        const size_t idx = (size_t)row * DM + c;
        const float v = (b2f(pparts[idx]) * w0 +
                         b2f(pparts[(size_t)M_DOC * DM + idx]) * w1 +
                         b2f(pparts[(size_t)2 * M_DOC * DM + idx]) * w2) / denom;
        ctx[idx] = __float2bfloat16(v);
    }
}

// ---------------------------------------------------------------------------
// LayerNorm over 768 with folded bias: x = A + acc1 + (acc2) + bias2.
//  MODE 0: A = flagged Xin -> bf16 ws out.
//  MODE 1: A = bf16 Xb     -> flagged-dtype d_out.
// Both modes sum Xf2f plus (optionally, non-null) Xf2g partials.
// zbuf (optional): zeroed after reads (atomic-fallback accumulator prep;
// may alias Xf2g — per-thread read-before-write at identical idx, safe).
// Wave shfl reduce + 1 barrier.
// ---------------------------------------------------------------------------
template<int MODE>
__global__ __launch_bounds__(256)
void ln_kernel(const void* __restrict__ Xin,
               const __hip_bfloat16* __restrict__ Xb,
               const float* __restrict__ Xf2f,
               const float* __restrict__ Xf2g,
               const void* __restrict__ bias2,
               const void* __restrict__ g,
               const void* __restrict__ be,
               __hip_bfloat16* __restrict__ outb,
               void* __restrict__ outv,
               float* __restrict__ zbuf,
               const int* __restrict__ flagp)
{
    __shared__ float red1[4], red2[4];
    const int f32 = *flagp;
    const int row = blockIdx.x;
    const int tid = threadIdx.x;
    const int lane = tid & 63;
    const int wave = tid >> 6;

    float x[3];
#pragma unroll
    for (int i = 0; i < 3; ++i) {
        int c = tid + i * 256;
        size_t idx = (size_t)row * DM + c;
        float a  = (MODE == 0) ? ldf(Xin, idx, f32) : b2f(Xb[idx]);
        float acc = Xf2f[idx];
        if (Xf2g) acc += Xf2g[idx];
        x[i] = a + acc + ldf(bias2, c, f32);
    }
    float s1 = x[0] + x[1] + x[2];
    float s2 = x[0] * x[0] + x[1] * x[1] + x[2] * x[2];
#pragma unroll
    for (int off = 32; off > 0; off >>= 1) {
        s1 += __shfl_xor(s1, off);
        s2 += __shfl_xor(s2, off);
    }
    if (lane == 0) { red1[wave] = s1; red2[wave] = s2; }
    __syncthreads();
    s1 = red1[0] + red1[1] + red1[2] + red1[3];
    s2 = red2[0] + red2[1] + red2[2] + red2[3];
    float mu   = s1 * (1.f / DM);
    float var  = s2 * (1.f / DM) - mu * mu;
    float rstd = rsqrtf(var + 1e-5f);
#pragma unroll
    for (int i = 0; i < 3; ++i) {
        int c = tid + i * 256;
        size_t idx = (size_t)row * DM + c;
        float v = (x[i] - mu) * rstd * ldf(g, c, f32) + ldf(be, c, f32);
        if (MODE == 0) {
            outb[idx] = __float2bfloat16(v);
        } else {
            if (f32) ((float*)outv)[idx] = v;
            else     ((__hip_bfloat16*)outv)[idx] = __float2bfloat16(v);
        }
        if (zbuf) zbuf[idx] = 0.f;
    }
}

// ---------------------------------------------------------------------------
extern "C" void kernel_launch(void* const* d_in, const int* in_sizes, int n_in,
                              void* d_out, int out_size, void* d_ws, size_t ws_size,
                              hipStream_t stream)
{
    const void* docqa = d_in[0];
    const void* im    = d_in[1];
    const int* dqx = (const int*)d_in[2];
    const int* dqy = (const int*)d_in[3];
    const int* imx = (const int*)d_in[4];
    const int* imy = (const int*)d_in[5];
    const void* Wq = d_in[6];
    const void* bq = d_in[7];
    const void* Wk = d_in[8];
    const void* bk = d_in[9];
    const void* Wv = d_in[10];
    const void* bv = d_in[11];
    const void* Wo = d_in[12];
    const void* bo = d_in[13];
    const void* bias_x = d_in[14];
    const void* bias_y = d_in[15];
    const void* W1 = d_in[16];
    const void* b1 = d_in[17];
    const void* W2 = d_in[18];
    const void* b2 = d_in[19];
    const void* g1  = d_in[20];
    const void* be1 = d_in[21];
    const void* g2  = d_in[22];
    const void* be2 = d_in[23];

    // Workspace pool: 39.6 MB, proven since round 3 (DO NOT GROW).
    //   flag @0; R1 3.93M; R2 11.89M; R3 11.89M; R4 11.89M   [bytes]
    // R1: Wt3 (dead after qkv) -> ml [1.18M,1.92M); cxy tail (dead after attn)
    //     -> WtO [0,1.18M) (dead after skWo) -> first part of mid
    // R2 (kb): k row-major (dead after attn) -> a0 f32 [0,7.86M) (skWo partial
    //     0, dead after LN1) -> rest of mid
    // R3 (vtb): V^T (dead after attn) -> W1t[0,4.72M)+W2t[4.72,9.44M)
    // R4 (cb): fullA (dead after qkv) -> p0/p1/p2 [0,11.79M) -> ctx/src1 (p0);
    //     a1 f32 [3.93,11.79M) (skWo partial 1, read by LN1) -> f0 (skF
    //     partial 0 / atomic acc, same region)
    // d_out: q bf16 scratch (dead after attn) -> f1 (skF partial 1, f32,
    //     only when out_size fits) -> final output (LN2; per-thread
    //     read-before-write at identical idx over f1)
    char* w = (char*)d_ws;
    int*            flagp = (int*)w;
    __hip_bfloat16* qR  = (__hip_bfloat16*)(w + 256);
    __hip_bfloat16* kb  = qR + (size_t)M_DOC  * DM;
    __hip_bfloat16* vtb = kb + (size_t)M_FULL * DM;
    __hip_bfloat16* cb  = vtb + (size_t)M_FULL * DM;
    char* cbB = (char*)cb;
    char* r1B = (char*)qR;

    __hip_bfloat16* fullA = cb;
    __hip_bfloat16* Wt3  = qR;
    int*            cxyp = (int*)(r1B + 3538944);     // R1 spare tail (31 KB)
    __hip_bfloat16* WtO  = qR;
    __hip_bfloat16* qout = (__hip_bfloat16*)d_out;
    __hip_bfloat16* pparts = cb;                      // 3 partials, contiguous
    float*          mlb  = (float*)(r1B + 1179648);   // over dead Wt3, after WtO
    __hip_bfloat16* ctx  = cb;
    __hip_bfloat16* src1 = cb;
    float*          a0   = (float*)kb;                // skWo partial 0 (R2)
    float*          a1   = (float*)(cbB + 3932160);   // skWo partial 1 (R4)
    float*          f0   = (float*)(cbB + 3932160);   // skF partial 0 (= a1 region, after LN1)
    __hip_bfloat16* W1t  = vtb;
    __hip_bfloat16* W2t  = vtb + (size_t)DFF * DM;
    __hip_bfloat16* mid  = qR;

    // skF direct-store partial 1 lives in d_out when the output buffer is
    // f32-sized; otherwise fall back to the atomic S=4 path.
    const bool skf_direct = (size_t)out_size >= (size_t)M_DOC * DM * sizeof(float);
    float* f1 = (float*)d_out;

    dim3 blk(256);

    // fused: flag + fullA conversion + packed coords + Wq/Wk/Wv transposes
    prep_wt3_kernel<<<dim3(NPREP + 3 * 576), blk, 0, stream>>>(
        g1, flagp, im, docqa, dqx, dqy, imx, imy, Wq, Wk, Wv, fullA, cxyp, Wt3);
    // fused q/k/v projection (R10 single-buffer structure)
    qkv_gemm<<<dim3(732 + 120), blk, 0, stream>>>(
        fullA, Wt3, bq, bk, bv, qout, kb, vtb, flagp);
    // attention, K-split S=3, double-buffered staging, 1 barrier/tile
    attn_part_kernel<<<dim3(48 * 30), blk, 0, stream>>>(
        qout, kb, vtb, cxyp, bias_x, bias_y, pparts, mlb, flagp);
    // fused: 3-way merge -> ctx + Wo transpose + W1/W2 transposes
    merge_wt_kernel<<<dim3(M_DOC + 576 + 4608), blk, 0, stream>>>(
        pparts, mlb, ctx, Wo, WtO, W1, W2, W1t, W2t, flagp);
    // attn_out: split-K S=2 DIRECT-STORE partials (R15-measured win)
    sk2_gemm<<<dim3(DM / 128, M_DOC / 128, 2), blk, 0, stream>>>(
        ctx, WtO, a0, a1, M_DOC, DM, DM);
    // src1 = LN(docqa + a0 + a1 + bo); zero f0 only if skF needs atomics
    ln_kernel<0><<<dim3(M_DOC), blk, 0, stream>>>(
        docqa, nullptr, a0, a1, bo, g1, be1, src1, nullptr,
        skf_direct ? nullptr : f0, flagp);
    // mid = relu(src1 @ W1 + b1) -> R1+R2 (WtO/cxy/ml/a0 dead)
    mfma_gemm_relu<<<dim3(DFF / 128, M_DOC / 128), blk, 0, stream>>>(
        src1, W1t, b1, mid, flagp, M_DOC, DFF, DM);
    if (skf_direct) {
        // ffn: split-K S=2 DIRECT-STORE partials f0 (R4) + f1 (d_out scratch)
        sk2_gemm<<<dim3(DM / 128, M_DOC / 128, 2), blk, 0, stream>>>(
            mid, W2t, f0, f1, M_DOC, DM, DFF);
        // out = LN(src1 + f0 + f1 + b2) -> d_out (reads f1 then overwrites)
        ln_kernel<1><<<dim3(M_DOC), blk, 0, stream>>>(
            nullptr, src1, f0, f1, b2, g2, be2, nullptr, d_out, nullptr, flagp);
    } else {
        // fallback: atomic S=4 into pre-zeroed f0
        sk_gemm<<<dim3(DM / 128, M_DOC / 128, 4), blk, 0, stream>>>(
            mid, W2t, f0, M_DOC, DM, DFF, 4);
        ln_kernel<1><<<dim3(M_DOC), blk, 0, stream>>>(
            nullptr, src1, f0, nullptr, b2, g2, be2, nullptr, d_out, nullptr, flagp);
    }
}